// Round 1
// baseline (257.025 us; speedup 1.0000x reference)
//
#include <hip/hip_runtime.h>
#include <hip/hip_bf16.h>
#include <cstdint>

// ---------------------------------------------------------------------------
// TagProjector fused kernel:
//   flat = tab[clamp(ids,0)]                  [51200, 512]  (gather, f32->bf16)
//   h    = gelu_tanh(flat @ w1 + b1)          [51200, 1024] (bf16 MFMA, LDS-chunked)
//   y    = h @ w2 + b2                        [51200, 256]  (bf16 MFMA, reg acc)
//   out  = mask ? 0 : y / max(||y||, 1e-12)   [51200, 256]  f32
// ---------------------------------------------------------------------------

typedef __bf16 bf16;
typedef bf16  bf16x8 __attribute__((ext_vector_type(8)));
typedef bf16  bf16x4 __attribute__((ext_vector_type(4)));
typedef float f32x4  __attribute__((ext_vector_type(4)));

#define D_IN    512
#define D_HID   1024
#define D_OUT   256
#define MT      64        // rows per workgroup
#define CHUNK   256       // N1 chunk width
#define NCH     4         // D_HID / CHUNK
#define NKS1    16        // D_IN / 32
#define NKS2C   8         // CHUNK / 32
#define THREADS 512

// LDS layout (bytes)
#define OFF_A    0                          // 64*512*2  = 65536  (A tile, swizzled)
#define OFF_H    65536                      // 64*256*2  = 32768  (h chunk, swizzled)
#define OFF_WB   (65536 + 32768)            // 2 * 16384 = 32768  (W frag double buffer)
#define OFF_NS   (65536 + 32768 + 32768)    // 64*8*4    = 2048   (norm partials)
#define OFF_RID  (65536 + 32768 + 32768 + 2048)  // 64*4 = 256    (row ids)
#define LDS_TOTAL (65536 + 32768 + 32768 + 2048 + 256)  // 133376

// ws layout: W1f bf16 [64 ct][16 ks][64 lane][8]  (1 MB)
//            W2f bf16 [16 ct][32 ks][64 lane][8]  (512 KB)
#define W1F_ELEMS (64 * 16 * 64 * 8)   // 524288

__device__ __forceinline__ void gld_lds16(const void* g, void* l) {
  __builtin_amdgcn_global_load_lds(
      (__attribute__((address_space(1))) uint32_t*)(uintptr_t)g,
      (__attribute__((address_space(3))) uint32_t*)(uintptr_t)l,
      16, 0, 0);
}

__device__ __forceinline__ float gelu_tanh(float x) {
  // jax.nn.gelu default (approximate=True): 0.5x(1+tanh(u)) == x*sigmoid(2u)
  float u = 0.7978845608028654f * (x + 0.044715f * x * x * x);
  return x / (1.0f + __expf(-2.0f * u));
}

// ------------------- prep: f32 weights -> bf16 fragment order -------------------
__global__ void prep_weights(const float* __restrict__ w1, const float* __restrict__ w2,
                             bf16* __restrict__ w1f, bf16* __restrict__ w2f) {
  const int t = blockIdx.x * blockDim.x + threadIdx.x;
  if (t < 65536) {                       // W1: 64 ct * 16 ks * 64 lanes
    const int l  = t & 63;
    const int ks = (t >> 6) & 15;
    const int ct = t >> 10;
    const int col   = ct * 16 + (l & 15);
    const int kbase = ks * 32 + (l >> 4) * 8;
    bf16x8 o;
#pragma unroll
    for (int j = 0; j < 8; ++j) o[j] = (bf16)w1[(size_t)(kbase + j) * D_HID + col];
    *(bf16x8*)(w1f + (size_t)t * 8) = o;
  } else if (t < 65536 + 32768) {        // W2: 16 ct * 32 ks * 64 lanes
    const int t2 = t - 65536;
    const int l   = t2 & 63;
    const int ks2 = (t2 >> 6) & 31;
    const int ct2 = t2 >> 11;
    const int col   = ct2 * 16 + (l & 15);
    const int kbase = ks2 * 32 + (l >> 4) * 8;
    bf16x8 o;
#pragma unroll
    for (int j = 0; j < 8; ++j) o[j] = (bf16)w2[(size_t)(kbase + j) * D_OUT + col];
    *(bf16x8*)(w2f + (size_t)t2 * 8) = o;
  }
}

// ----------------------------- fused main kernel --------------------------------
__global__ __launch_bounds__(THREADS, 2)
void tagproj_fused(const float* __restrict__ tab, const int* __restrict__ ids,
                   const bf16* __restrict__ w1f, const bf16* __restrict__ w2f,
                   const float* __restrict__ b1, const float* __restrict__ b2,
                   float* __restrict__ out) {
  extern __shared__ __align__(16) char lds[];
  bf16*  As  = (bf16*)(lds + OFF_A);
  bf16*  Hs  = (bf16*)(lds + OFF_H);
  bf16*  Wb  = (bf16*)(lds + OFF_WB);
  float* Ns  = (float*)(lds + OFF_NS);
  int*   Rid = (int*)(lds + OFF_RID);

  const int tid = threadIdx.x;
  const int w   = tid >> 6;   // wave 0..7
  const int l   = tid & 63;
  const int lg  = l >> 4;     // k-group 0..3
  const int lc  = l & 15;     // row/col within 16-tile
  const int m0  = blockIdx.x * MT;

  // ---- A gather: 64 rows x 512 f32 -> bf16 swizzled LDS ----
  {
    const int row = tid >> 3;        // 8 threads per row
    const int q   = tid & 7;
    const int id  = ids[m0 + row];
    if (q == 0) Rid[row] = id;
    const float* src = tab + (size_t)(id < 0 ? 0 : id) * D_IN;
#pragma unroll
    for (int i = 0; i < 16; ++i) {
      const int c4 = i * 32 + q * 4;
      const float4 v = *(const float4*)(src + c4);
      bf16x4 b;
      b[0] = (bf16)v.x; b[1] = (bf16)v.y; b[2] = (bf16)v.z; b[3] = (bf16)v.w;
      *(bf16x4*)&As[row * 512 + (c4 ^ ((row & 15) << 3))] = b;
    }
  }

  // persistent GEMM2 accumulators: rows rt*16+lg*4+r, cols (w*2+t)*16+lc
  f32x4 acc2[4][2];
#pragma unroll
  for (int rt = 0; rt < 4; ++rt)
#pragma unroll
    for (int t = 0; t < 2; ++t) acc2[rt][t] = (f32x4){0.f, 0.f, 0.f, 0.f};

  for (int c = 0; c < NCH; ++c) {
    // ---- stage W1(c, ks=0) -> buf0 ----
#pragma unroll
    for (int s = 0; s < 2; ++s) {
      const int pos = w * 2 + s;
      gld_lds16(w1f + (((size_t)(c * 16 + pos) * 16 + 0) * 64 + l) * 8,
                Wb + pos * 512);
    }
    __syncthreads();

    // ---- GEMM1: h_chunk(64 x 256) = A(64 x 512) @ W1[:, c*256:+256] ----
    f32x4 acc1[4][2];
#pragma unroll
    for (int rt = 0; rt < 4; ++rt)
#pragma unroll
      for (int t = 0; t < 2; ++t) acc1[rt][t] = (f32x4){0.f, 0.f, 0.f, 0.f};

    for (int ks = 0; ks < NKS1; ++ks) {
      const int buf = ks & 1;
      if (ks + 1 < NKS1) {
#pragma unroll
        for (int s = 0; s < 2; ++s) {
          const int pos = w * 2 + s;
          gld_lds16(w1f + (((size_t)(c * 16 + pos) * 16 + (ks + 1)) * 64 + l) * 8,
                    Wb + (buf ^ 1) * 8192 + pos * 512);
        }
      }
      bf16x8 af[4];
#pragma unroll
      for (int rt = 0; rt < 4; ++rt) {
        const int row = rt * 16 + lc;
        const int e   = ks * 32 + lg * 8;
        af[rt] = *(const bf16x8*)&As[row * 512 + (e ^ ((row & 15) << 3))];
      }
#pragma unroll
      for (int t = 0; t < 2; ++t) {
        const bf16x8 bfr = *(const bf16x8*)&Wb[buf * 8192 + (w * 2 + t) * 512 + l * 8];
#pragma unroll
        for (int rt = 0; rt < 4; ++rt)
          acc1[rt][t] = __builtin_amdgcn_mfma_f32_16x16x32_bf16(af[rt], bfr, acc1[rt][t], 0, 0, 0);
      }
      __syncthreads();
    }

    // ---- bias + GELU -> bf16 h chunk in LDS (swizzled) ----
#pragma unroll
    for (int t = 0; t < 2; ++t) {
      const int pos  = w * 2 + t;
      const float bias = b1[c * CHUNK + pos * 16 + lc];
#pragma unroll
      for (int rt = 0; rt < 4; ++rt) {
#pragma unroll
        for (int r = 0; r < 4; ++r) {
          const float x  = acc1[rt][t][r] + bias;
          const float hx = gelu_tanh(x);
          const int row  = rt * 16 + lg * 4 + r;
          const int e    = pos * 16 + lc;
          Hs[row * 256 + (e ^ ((row & 15) << 3))] = (bf16)hx;
        }
      }
    }
    // ---- stage W2(c, s2=0) -> buf0 ----
#pragma unroll
    for (int s = 0; s < 2; ++s) {
      const int pos = w * 2 + s;
      gld_lds16(w2f + (((size_t)pos * 32 + (c * 8 + 0)) * 64 + l) * 8,
                Wb + pos * 512);
    }
    __syncthreads();  // h visible + W2 buf0 ready

    // ---- GEMM2: y(64 x 256) += h_chunk(64 x 256) @ W2[c*256:+256, :] ----
    for (int s2 = 0; s2 < NKS2C; ++s2) {
      const int buf = s2 & 1;
      if (s2 + 1 < NKS2C) {
#pragma unroll
        for (int s = 0; s < 2; ++s) {
          const int pos = w * 2 + s;
          gld_lds16(w2f + (((size_t)pos * 32 + (c * 8 + s2 + 1)) * 64 + l) * 8,
                    Wb + (buf ^ 1) * 8192 + pos * 512);
        }
      }
      bf16x8 hf[4];
#pragma unroll
      for (int rt = 0; rt < 4; ++rt) {
        const int row = rt * 16 + lc;
        const int e   = s2 * 32 + lg * 8;
        hf[rt] = *(const bf16x8*)&Hs[row * 256 + (e ^ ((row & 15) << 3))];
      }
#pragma unroll
      for (int t = 0; t < 2; ++t) {
        const bf16x8 bfr = *(const bf16x8*)&Wb[buf * 8192 + (w * 2 + t) * 512 + l * 8];
#pragma unroll
        for (int rt = 0; rt < 4; ++rt)
          acc2[rt][t] = __builtin_amdgcn_mfma_f32_16x16x32_bf16(hf[rt], bfr, acc2[rt][t], 0, 0, 0);
      }
      __syncthreads();
    }
  }

  // ---- epilogue: +b2, row L2-norm, pad mask, store ----
  float yv[4][2][4];
  float ssq[4][4];
#pragma unroll
  for (int rt = 0; rt < 4; ++rt)
#pragma unroll
    for (int r = 0; r < 4; ++r) ssq[rt][r] = 0.f;

#pragma unroll
  for (int t = 0; t < 2; ++t) {
    const float bias = b2[(w * 2 + t) * 16 + lc];
#pragma unroll
    for (int rt = 0; rt < 4; ++rt)
#pragma unroll
      for (int r = 0; r < 4; ++r) {
        const float v = acc2[rt][t][r] + bias;
        yv[rt][t][r] = v;
        ssq[rt][r] += v * v;
      }
  }
#pragma unroll
  for (int rt = 0; rt < 4; ++rt)
#pragma unroll
    for (int r = 0; r < 4; ++r) {
      float s = ssq[rt][r];
      s += __shfl_xor(s, 1);
      s += __shfl_xor(s, 2);
      s += __shfl_xor(s, 4);
      s += __shfl_xor(s, 8);
      ssq[rt][r] = s;   // per-wave partial (32 of 256 cols), same for all lc in group
    }
  if (lc == 0) {
#pragma unroll
    for (int rt = 0; rt < 4; ++rt)
#pragma unroll
      for (int r = 0; r < 4; ++r)
        Ns[(rt * 16 + lg * 4 + r) * 8 + w] = ssq[rt][r];
  }
  __syncthreads();

#pragma unroll
  for (int rt = 0; rt < 4; ++rt)
#pragma unroll
    for (int r = 0; r < 4; ++r) {
      const int row = rt * 16 + lg * 4 + r;
      float ss = 0.f;
#pragma unroll
      for (int ww = 0; ww < 8; ++ww) ss += Ns[row * 8 + ww];
      const float scale = (Rid[row] < 0) ? 0.f : (1.f / fmaxf(sqrtf(ss), 1e-12f));
#pragma unroll
      for (int t = 0; t < 2; ++t)
        out[(size_t)(m0 + row) * D_OUT + (w * 2 + t) * 16 + lc] = yv[rt][t][r] * scale;
    }
}

// --------------------------------- launcher ---------------------------------
extern "C" void kernel_launch(void* const* d_in, const int* in_sizes, int n_in,
                              void* d_out, int out_size, void* d_ws, size_t ws_size,
                              hipStream_t stream) {
  const float* tab = (const float*)d_in[0];
  const float* w1  = (const float*)d_in[1];
  const float* b1  = (const float*)d_in[2];
  const float* w2  = (const float*)d_in[3];
  const float* b2  = (const float*)d_in[4];
  const int*   ids = (const int*)d_in[5];
  float* out = (float*)d_out;

  bf16* w1f = (bf16*)d_ws;
  bf16* w2f = w1f + W1F_ELEMS;

  hipLaunchKernelGGL(prep_weights, dim3(384), dim3(256), 0, stream, w1, w2, w1f, w2f);

  (void)hipFuncSetAttribute(reinterpret_cast<const void*>(tagproj_fused),
                            hipFuncAttributeMaxDynamicSharedMemorySize, LDS_TOTAL);
  hipLaunchKernelGGL(tagproj_fused, dim3(51200 / MT), dim3(THREADS), LDS_TOTAL, stream,
                     tab, ids, w1f, w2f, b1, b2, out);
}

// Round 2
// 183.254 us; speedup vs baseline: 1.4026x; 1.4026x over previous
//
#include <hip/hip_runtime.h>
#include <hip/hip_bf16.h>
#include <cstdint>

// ---------------------------------------------------------------------------
// TagProjector fused kernel (R2):
//   flat = tab[clamp(ids,0)]                  [51200, 512]  (gather, f32->bf16)
//   h    = gelu_tanh(flat @ w1 + b1)          [51200, 1024] (bf16 MFMA)
//   y    = h @ w2 + b2                        [51200, 256]  (bf16 MFMA, reg acc)
//   out  = mask ? 0 : y / max(||y||, 1e-12)   [51200, 256]  f32
//
// R2 changes vs R1: W fragments read directly from global (L2-resident) into
// registers with depth-2 prefetch — no W LDS staging, no per-k-step barriers.
// H double-buffered -> 1 barrier per chunk (5 barriers/block total vs ~101).
// ---------------------------------------------------------------------------

typedef __bf16 bf16;
typedef bf16  bf16x8 __attribute__((ext_vector_type(8)));
typedef bf16  bf16x4 __attribute__((ext_vector_type(4)));
typedef float f32x4  __attribute__((ext_vector_type(4)));

#define D_IN    512
#define D_HID   1024
#define D_OUT   256
#define MT      64        // rows per workgroup
#define CHUNK   256       // N1 chunk width
#define NCH     4         // D_HID / CHUNK
#define NKS1    16        // D_IN / 32
#define NKS2C   8         // CHUNK / 32
#define THREADS 512

// LDS layout (bytes)
#define OFF_A    0                          // 64*512*2       = 65536 (A tile, swizzled)
#define OFF_H    65536                      // 2 * 64*256*2   = 65536 (H chunk, double buffer)
#define OFF_NS   (65536 + 65536)            // 64*8*4         = 2048  (norm partials)
#define OFF_RID  (65536 + 65536 + 2048)     // 64*4           = 256   (row ids)
#define LDS_TOTAL (65536 + 65536 + 2048 + 256)   // 133376

// ws layout: W1f bf16 [64 ct][16 ks][64 lane][8]  (1 MB)
//            W2f bf16 [16 ct][32 ks][64 lane][8]  (512 KB)
#define W1F_ELEMS (64 * 16 * 64 * 8)   // 524288

__device__ __forceinline__ float gelu_tanh(float x) {
  // jax.nn.gelu default (approximate=True): 0.5x(1+tanh(u)) == x*sigmoid(2u)
  float u = 0.7978845608028654f * (x + 0.044715f * x * x * x);
  return x * __builtin_amdgcn_rcpf(1.0f + __expf(-2.0f * u));
}

// ------------------- prep: f32 weights -> bf16 fragment order -------------------
__global__ void prep_weights(const float* __restrict__ w1, const float* __restrict__ w2,
                             bf16* __restrict__ w1f, bf16* __restrict__ w2f) {
  const int t = blockIdx.x * blockDim.x + threadIdx.x;
  if (t < 65536) {                       // W1: 64 ct * 16 ks * 64 lanes
    const int l  = t & 63;
    const int ks = (t >> 6) & 15;
    const int ct = t >> 10;
    const int col   = ct * 16 + (l & 15);
    const int kbase = ks * 32 + (l >> 4) * 8;
    bf16x8 o;
#pragma unroll
    for (int j = 0; j < 8; ++j) o[j] = (bf16)w1[(size_t)(kbase + j) * D_HID + col];
    *(bf16x8*)(w1f + (size_t)t * 8) = o;
  } else if (t < 65536 + 32768) {        // W2: 16 ct * 32 ks * 64 lanes
    const int t2 = t - 65536;
    const int l   = t2 & 63;
    const int ks2 = (t2 >> 6) & 31;
    const int ct2 = t2 >> 11;
    const int col   = ct2 * 16 + (l & 15);
    const int kbase = ks2 * 32 + (l >> 4) * 8;
    bf16x8 o;
#pragma unroll
    for (int j = 0; j < 8; ++j) o[j] = (bf16)w2[(size_t)(kbase + j) * D_OUT + col];
    *(bf16x8*)(w2f + (size_t)t2 * 8) = o;
  }
}

// ----------------------------- fused main kernel --------------------------------
__global__ __launch_bounds__(THREADS, 2)
void tagproj_fused(const float* __restrict__ tab, const int* __restrict__ ids,
                   const bf16* __restrict__ w1f, const bf16* __restrict__ w2f,
                   const float* __restrict__ b1, const float* __restrict__ b2,
                   float* __restrict__ out) {
  extern __shared__ __align__(16) char lds[];
  bf16*  As  = (bf16*)(lds + OFF_A);
  bf16*  Hb  = (bf16*)(lds + OFF_H);
  float* Ns  = (float*)(lds + OFF_NS);
  int*   Rid = (int*)(lds + OFF_RID);

  const int tid = threadIdx.x;
  const int w   = tid >> 6;   // wave 0..7
  const int l   = tid & 63;
  const int lg  = l >> 4;     // k-group 0..3
  const int lc  = l & 15;     // row/col within 16-tile
  const int m0  = blockIdx.x * MT;

  // ---- A gather: 64 rows x 512 f32 -> bf16 swizzled LDS ----
  {
    const int row = tid >> 3;        // 8 threads per row
    const int q   = tid & 7;
    const int id  = ids[m0 + row];
    if (q == 0) Rid[row] = id;
    const float* src = tab + (size_t)(id < 0 ? 0 : id) * D_IN;
#pragma unroll
    for (int i = 0; i < 16; ++i) {
      const int c4 = i * 32 + q * 4;
      const float4 v = *(const float4*)(src + c4);
      bf16x4 b;
      b[0] = (bf16)v.x; b[1] = (bf16)v.y; b[2] = (bf16)v.z; b[3] = (bf16)v.w;
      *(bf16x4*)&As[row * 512 + (c4 ^ ((row & 15) << 3))] = b;
    }
  }
  __syncthreads();

  // persistent GEMM2 accumulators: rows rt*16+lg*4+r, cols (w*2+t)*16+lc
  f32x4 acc2[4][2];
#pragma unroll
  for (int rt = 0; rt < 4; ++rt)
#pragma unroll
    for (int t = 0; t < 2; ++t) acc2[rt][t] = (f32x4){0.f, 0.f, 0.f, 0.f};

  for (int c = 0; c < NCH; ++c) {
    bf16* Hs = Hb + (c & 1) * (MT * CHUNK);

    // ===== GEMM1: h_chunk(64x256) = A(64x512) @ W1[:, c*256:+256] =====
    // W1 fragments from global (L2-hit), depth-2 rotating prefetch.
    f32x4 acc1[4][2];
#pragma unroll
    for (int rt = 0; rt < 4; ++rt)
#pragma unroll
      for (int t = 0; t < 2; ++t) acc1[rt][t] = (f32x4){0.f, 0.f, 0.f, 0.f};

    // frag address: ((ct*16 + ks)*64 + l)*8, ct = c*16 + w*2 + t
    const bf16* w1p = w1f + (((size_t)(c * 16 + w * 2) * 16) * 64 + l) * 8;
    // per-t stride: 16*64*8 = 8192 elems; per-ks stride: 64*8 = 512 elems

    bf16x8 wr1[4][2];
#pragma unroll
    for (int pf = 0; pf < 2; ++pf)
#pragma unroll
      for (int t = 0; t < 2; ++t)
        wr1[pf][t] = *(const bf16x8*)(w1p + (size_t)t * 8192 + (size_t)pf * 512);

#pragma unroll
    for (int ks = 0; ks < NKS1; ++ks) {
      if (ks + 2 < NKS1) {
#pragma unroll
        for (int t = 0; t < 2; ++t)
          wr1[(ks + 2) & 3][t] =
              *(const bf16x8*)(w1p + (size_t)t * 8192 + (size_t)(ks + 2) * 512);
      }
      bf16x8 af[4];
#pragma unroll
      for (int rt = 0; rt < 4; ++rt) {
        const int e = ks * 32 + lg * 8;
        af[rt] = *(const bf16x8*)&As[(rt * 16 + lc) * 512 + (e ^ (lc << 3))];
      }
#pragma unroll
      for (int t = 0; t < 2; ++t)
#pragma unroll
        for (int rt = 0; rt < 4; ++rt)
          acc1[rt][t] = __builtin_amdgcn_mfma_f32_16x16x32_bf16(
              af[rt], wr1[ks & 3][t], acc1[rt][t], 0, 0, 0);
    }

    // ---- bias + GELU -> bf16 h chunk in LDS (swizzled, double-buffered) ----
#pragma unroll
    for (int t = 0; t < 2; ++t) {
      const int pos    = w * 2 + t;
      const float bias = b1[c * CHUNK + pos * 16 + lc];
#pragma unroll
      for (int rt = 0; rt < 4; ++rt) {
#pragma unroll
        for (int r = 0; r < 4; ++r) {
          const float x  = acc1[rt][t][r] + bias;
          const float hx = gelu_tanh(x);
          const int row  = rt * 16 + lg * 4 + r;
          const int e    = pos * 16 + lc;
          Hs[row * 256 + (e ^ ((row & 15) << 3))] = (bf16)hx;
        }
      }
    }
    __syncthreads();   // h chunk visible; the only barrier in the chunk loop

    // ===== GEMM2: y(64x256) += h_chunk(64x256) @ W2[c*256:+256, :] =====
    const bf16* w2p = w2f + (((size_t)(w * 2) * 32 + c * 8) * 64 + l) * 8;
    // per-t stride: 32*64*8 = 16384 elems; per-s2 stride: 64*8 = 512 elems

    bf16x8 wr2[4][2];
#pragma unroll
    for (int pf = 0; pf < 2; ++pf)
#pragma unroll
      for (int t = 0; t < 2; ++t)
        wr2[pf][t] = *(const bf16x8*)(w2p + (size_t)t * 16384 + (size_t)pf * 512);

#pragma unroll
    for (int s2 = 0; s2 < NKS2C; ++s2) {
      if (s2 + 2 < NKS2C) {
#pragma unroll
        for (int t = 0; t < 2; ++t)
          wr2[(s2 + 2) & 3][t] =
              *(const bf16x8*)(w2p + (size_t)t * 16384 + (size_t)(s2 + 2) * 512);
      }
      bf16x8 hf[4];
#pragma unroll
      for (int rt = 0; rt < 4; ++rt) {
        const int e = s2 * 32 + lg * 8;
        hf[rt] = *(const bf16x8*)&Hs[(rt * 16 + lc) * 256 + (e ^ (lc << 3))];
      }
#pragma unroll
      for (int t = 0; t < 2; ++t)
#pragma unroll
        for (int rt = 0; rt < 4; ++rt)
          acc2[rt][t] = __builtin_amdgcn_mfma_f32_16x16x32_bf16(
              hf[rt], wr2[s2 & 3][t], acc2[rt][t], 0, 0, 0);
    }
  }

  // ---- epilogue: +b2, row L2-norm, pad mask, store ----
  float yv[4][2][4];
  float ssq[4][4];
#pragma unroll
  for (int rt = 0; rt < 4; ++rt)
#pragma unroll
    for (int r = 0; r < 4; ++r) ssq[rt][r] = 0.f;

#pragma unroll
  for (int t = 0; t < 2; ++t) {
    const float bias = b2[(w * 2 + t) * 16 + lc];
#pragma unroll
    for (int rt = 0; rt < 4; ++rt)
#pragma unroll
      for (int r = 0; r < 4; ++r) {
        const float v = acc2[rt][t][r] + bias;
        yv[rt][t][r] = v;
        ssq[rt][r] += v * v;
      }
  }
#pragma unroll
  for (int rt = 0; rt < 4; ++rt)
#pragma unroll
    for (int r = 0; r < 4; ++r) {
      float s = ssq[rt][r];
      s += __shfl_xor(s, 1);
      s += __shfl_xor(s, 2);
      s += __shfl_xor(s, 4);
      s += __shfl_xor(s, 8);
      ssq[rt][r] = s;   // per-wave partial (32 of 256 cols)
    }
  if (lc == 0) {
#pragma unroll
    for (int rt = 0; rt < 4; ++rt)
#pragma unroll
      for (int r = 0; r < 4; ++r)
        Ns[(rt * 16 + lg * 4 + r) * 8 + w] = ssq[rt][r];
  }
  __syncthreads();

#pragma unroll
  for (int rt = 0; rt < 4; ++rt)
#pragma unroll
    for (int r = 0; r < 4; ++r) {
      const int row = rt * 16 + lg * 4 + r;
      float ss = 0.f;
#pragma unroll
      for (int ww = 0; ww < 8; ++ww) ss += Ns[row * 8 + ww];
      const float scale = (Rid[row] < 0) ? 0.f : (1.f / fmaxf(sqrtf(ss), 1e-12f));
#pragma unroll
      for (int t = 0; t < 2; ++t)
        out[(size_t)(m0 + row) * D_OUT + (w * 2 + t) * 16 + lc] = yv[rt][t][r] * scale;
    }
}

// --------------------------------- launcher ---------------------------------
extern "C" void kernel_launch(void* const* d_in, const int* in_sizes, int n_in,
                              void* d_out, int out_size, void* d_ws, size_t ws_size,
                              hipStream_t stream) {
  const float* tab = (const float*)d_in[0];
  const float* w1  = (const float*)d_in[1];
  const float* b1  = (const float*)d_in[2];
  const float* w2  = (const float*)d_in[3];
  const float* b2  = (const float*)d_in[4];
  const int*   ids = (const int*)d_in[5];
  float* out = (float*)d_out;

  bf16* w1f = (bf16*)d_ws;
  bf16* w2f = w1f + W1F_ELEMS;

  hipLaunchKernelGGL(prep_weights, dim3(384), dim3(256), 0, stream, w1, w2, w1f, w2f);

  (void)hipFuncSetAttribute(reinterpret_cast<const void*>(tagproj_fused),
                            hipFuncAttributeMaxDynamicSharedMemorySize, LDS_TOTAL);
  hipLaunchKernelGGL(tagproj_fused, dim3(51200 / MT), dim3(THREADS), LDS_TOTAL, stream,
                     tab, ids, w1f, w2f, b1, b2, out);
}